// Round 19
// baseline (28.451 us; speedup 1.0000x reference)
//
#include <hip/hip_runtime.h>

#define RS 7
#define SR 2
#define PD 10
#define CH 490
#define SCALE (1.0f / 16.0f)
#define HH 100
#define WW 100
#define NPLANE 10000
#define PSLOT 2559            // 16B slots per plane region (2500 data + 59 pad)
#define PAIRSLOT 5118         // slots per pair buffer (81888 B)
#define PFLOAT (PSLOT * 4)    // 10236 floats: plane-B base within pair buffer
#define BUFFLT (PAIRSLOT * 4) // 20472 floats per pair buffer
#define TPB 1024
#define NBLK 256
#define NB 4
#define MAXN 4096
#define RSL 2                 // register param slots (covers cnt <= 2048)

// async global->LDS, 16B per lane; LDS dest WAVE-UNIFORM base (+lane*16 by HW);
// global source address is PER-LANE.
__device__ __forceinline__ void gll16(const void* g, void* l) {
    __builtin_amdgcn_global_load_lds(
        (const __attribute__((address_space(1))) void*)g,
        (__attribute__((address_space(3))) void*)l, 16, 0, 0);
}

__device__ __forceinline__ void waitv(int allowed) {
    switch (allowed) {
        case 0: asm volatile("s_waitcnt vmcnt(0)" ::: "memory"); break;
        case 1: asm volatile("s_waitcnt vmcnt(1)" ::: "memory"); break;
        case 2: asm volatile("s_waitcnt vmcnt(2)" ::: "memory"); break;
        case 3: asm volatile("s_waitcnt vmcnt(3)" ::: "memory"); break;
        case 4: asm volatile("s_waitcnt vmcnt(4)" ::: "memory"); break;
        case 5: asm volatile("s_waitcnt vmcnt(5)" ::: "memory"); break;
        default: asm volatile("s_waitcnt vmcnt(0)" ::: "memory"); break;
    }
}

__device__ __forceinline__ float psroi_sample_f32(const float* __restrict__ plane,
                                                  float sw, float sh, float bw, float bh,
                                                  int ph, int pw)
{
    float acc = 0.0f;
    #pragma unroll
    for (int iy = 0; iy < SR; ++iy) {
        float y  = sh + ((float)ph + ((float)iy + 0.5f) * (1.0f / SR)) * bh;
        bool  vy = (y >= -1.0f) && (y <= (float)HH);
        float yy = fmaxf(y, 0.0f);
        int   y0 = min((int)floorf(yy), HH - 1);
        int   y1 = min(y0 + 1, HH - 1);
        float yc = (y0 >= HH - 1) ? (float)y0 : yy;
        float ly = yc - (float)y0;
        float hy = 1.0f - ly;
        #pragma unroll
        for (int ix = 0; ix < SR; ++ix) {
            float x  = sw + ((float)pw + ((float)ix + 0.5f) * (1.0f / SR)) * bw;
            bool  vx = (x >= -1.0f) && (x <= (float)WW);
            float xx = fmaxf(x, 0.0f);
            int   x0 = min((int)floorf(xx), WW - 1);
            int   x1 = min(x0 + 1, WW - 1);
            float xc = (x0 >= WW - 1) ? (float)x0 : xx;
            float lx = xc - (float)x0;
            float hx = 1.0f - lx;
            float v00 = plane[y0 * WW + x0];
            float v01 = plane[y0 * WW + x1];
            float v10 = plane[y1 * WW + x0];
            float v11 = plane[y1 * WW + x1];
            float v = hy * (hx * v00 + lx * v01) + ly * (hx * v10 + lx * v11);
            if (vy && vx) acc += v;
        }
    }
    return acc * (1.0f / (SR * SR));
}

// persistent pair-tile pipeline: 256 blocks (1/CU) x 1024 thr, 3-4 pair-tiles
// per block.  Pair (cinA, cinA+245) shares (ph,pw) -> coords computed once.
// 2 buffers: stage(k+2) is issued AFTER compute(k)'s barrier (freed buffer).
__global__ __launch_bounds__(TPB) void psroi_pair_pipe_kernel(
    const float* __restrict__ feat, const float* __restrict__ rois,
    float* __restrict__ out, int N)
{
    __shared__ __align__(16) float bufA[BUFFLT];   // 81888 B
    __shared__ __align__(16) float bufB[BUFFLT];   // 81888 B
    __shared__ int lcnt;                           // total 163780 B <= 160 KiB

    int tid  = threadIdx.x;
    int wid  = tid >> 6;
    int lane = tid & 63;
    int bid  = blockIdx.x;
    int xcd  = bid & 7;                      // heuristic XCD id (perf-only)
    int b    = xcd >> 1;                     // 2 XCDs per batch
    int j    = ((xcd & 1) << 5) | (bid >> 3);// 0..63 within batch
    int nt   = (j <= 52) ? 4 : 3;            // pairs: cinA = j + k*64, 245 = 3*64+53

    if (tid == 0) lcnt = 0;
    __syncthreads();

    // ---- 1) latency-flat scan: prefetch ids, ballot-compact list into bufA ----
    float bf[4];
    #pragma unroll
    for (int s = 0; s < 4; ++s) {
        int k = s * TPB + tid;
        bf[s] = (k < N) ? rois[(size_t)k * 5] : -1.0f;
    }
    int* list = (int*)bufA;
    #pragma unroll
    for (int s = 0; s < 4; ++s) {
        int k = s * TPB + tid;
        bool m = (k < N) && ((int)bf[s] == b);
        unsigned long long msk = __ballot(m);
        if (m) {
            int rank   = __popcll(msk & ((1ull << lane) - 1ull));
            int leader = __ffsll((long long)msk) - 1;
            int pos = 0;
            if (lane == leader) pos = atomicAdd(&lcnt, (int)__popcll(msk));
            pos = __shfl(pos, leader) + rank;
            list[pos] = k;
        }
    }
    __syncthreads();
    int cnt = lcnt;

    // ---- 2) my ROI params -> registers ----
    float psw[RSL], psh[RSL], pbw[RSL], pbh[RSL];
    int   pn[RSL];
    #pragma unroll
    for (int s = 0; s < RSL; ++s) {
        int i = tid + s * TPB;
        pn[s] = -1;
        psw[s] = psh[s] = pbw[s] = pbh[s] = 0.0f;
        if (i < cnt) {
            int n = list[i];
            pn[s] = n;
            const float* rp = rois + (size_t)n * 5;
            float sw = rp[1] * SCALE - 0.5f;
            float sh = rp[2] * SCALE - 0.5f;
            psw[s] = sw;
            psh[s] = sh;
            pbw[s] = (rp[3] * SCALE - 0.5f - sw) * (1.0f / RS);
            pbh[s] = (rp[4] * SCALE - 0.5f - sh) * (1.0f / RS);
        }
    }
    __syncthreads();                         // all list reads done before staging

    // wave-uniform store-instruction count per pair-tile (2 stores per slot)
    int wave_first = tid & ~63;
    int slots_active = 0;
    #pragma unroll
    for (int s = 0; s < RSL; ++s) if (wave_first + s * TPB < cnt) ++slots_active;
    int wstores = 2 * slots_active;

    // ---- 3) pair stage: exactly 5 glls per wave; per-lane A/B source select ----
    auto stage = [&](float* dst, int cinA) {
        const char* gA = (const char*)(feat + (size_t)(b * CH + cinA) * NPLANE);
        const char* gB = gA + (size_t)245 * NPLANE * 4;
        char* ls = (char*)dst;
        #pragma unroll
        for (int r = 0; r < 5; ++r) {
            int wbase = r * TPB + (wid << 6);
            if (r == 4 && wid == 15) wbase = 5054;   // shifted window (dup = same data)
            int slot = wbase + lane;
            bool pl  = slot >= PSLOT;
            int  off = min(pl ? slot - PSLOT : slot, 2499);  // clamp: pad gets junk
            const char* src = (pl ? gB : gA) + (size_t)off * 16;
            gll16(src, ls + (size_t)wbase * 16);
        }
    };

    stage(bufA, j);                          // pair-tile 0
    if (nt > 1) stage(bufB, j + 64);         // pair-tile 1
    waitv(nt > 1 ? 5 : 0);                   // tile0 resident; tile1 in flight
    __builtin_amdgcn_s_barrier();
    __builtin_amdgcn_sched_barrier(0);

    // ---- 4) pipelined pair-tile loop (stage k+2 AFTER compute(k) frees buffer) ----
    for (int k = 0; k < nt; ++k) {
        const float* __restrict__ bc = (k & 1) ? bufB : bufA;
        int cinA = j + k * 64;
        int pp   = cinA % 49;
        int ph   = pp / 7, pw = pp - ph * 7;

        #pragma unroll
        for (int s = 0; s < RSL; ++s) {
            if (pn[s] >= 0) {
                float sw = psw[s], sh = psh[s], bw = pbw[s], bh = pbh[s];
                float accA = 0.0f, accB = 0.0f;
                #pragma unroll
                for (int iy = 0; iy < SR; ++iy) {
                    float y  = sh + ((float)ph + ((float)iy + 0.5f) * (1.0f / SR)) * bh;
                    bool  vy = (y >= -1.0f) && (y <= (float)HH);
                    float yy = fmaxf(y, 0.0f);
                    int   y0 = min((int)floorf(yy), HH - 1);
                    float yc = (y0 >= HH - 1) ? (float)y0 : yy;
                    float ly = yc - (float)y0;
                    float hy = 1.0f - ly;
                    #pragma unroll
                    for (int ix = 0; ix < SR; ++ix) {
                        float x  = sw + ((float)pw + ((float)ix + 0.5f) * (1.0f / SR)) * bw;
                        bool  vx = (x >= -1.0f) && (x <= (float)WW);
                        float xx = fmaxf(x, 0.0f);
                        int   x0 = min((int)floorf(xx), WW - 1);
                        float xc = (x0 >= WW - 1) ? (float)x0 : xx;
                        float lx = xc - (float)x0;
                        float hx = 1.0f - lx;
                        float w00 = hy * hx, w01 = hy * lx, w10 = ly * hx, w11 = ly * lx;
                        // clamp-by-weight: stray taps (pad/junk) carry weight 0
                        int o = y0 * WW + x0;
                        if (vy && vx) {
                            accA += w00 * bc[o]      + w01 * bc[o + 1]
                                  + w10 * bc[o + WW] + w11 * bc[o + WW + 1];
                            const float* bB = bc + PFLOAT;
                            accB += w00 * bB[o]      + w01 * bB[o + 1]
                                  + w10 * bB[o + WW] + w11 * bB[o + WW + 1];
                        }
                    }
                }
                size_t obase = (size_t)pn[s] * CH + cinA;
                out[obase]       = accA * (1.0f / (SR * SR));
                out[obase + 245] = accB * (1.0f / (SR * SR));
            }
        }

        if (k + 1 < nt) {
            // stage(k+1) glls are OLDER than this tile's stores: waiting down to
            // wstores retires them (tile k+1 resident), leaving stores in flight.
            waitv(wstores);
            __builtin_amdgcn_s_barrier();          // buffer of tile k now free
            __builtin_amdgcn_sched_barrier(0);
            if (k + 2 < nt) {
                stage((k & 1) ? bufB : bufA, j + (k + 2) * 64);  // into freed buffer
                __builtin_amdgcn_sched_barrier(0); // issue before compute(k+1)
            }
        }
    }

    // ---- pathological overflow (cnt > RSL*TPB): direct recompute (idempotent) ----
    if (cnt > RSL * TPB) {
        for (int k = 0; k < nt; ++k) {
            int cinA = j + k * 64;
            int pp = cinA % 49;
            int ph = pp / 7, pw = pp - ph * 7;
            const float* baseA = feat + (size_t)(b * CH + cinA) * NPLANE;
            const float* baseB = baseA + (size_t)245 * NPLANE;
            int seen = 0;
            for (int n = 0; n < N; ++n) {
                if ((int)rois[(size_t)n * 5] != b) continue;
                if (seen >= RSL * TPB && ((seen - RSL * TPB) % TPB) == tid) {
                    const float* rp = rois + (size_t)n * 5;
                    float sw = rp[1] * SCALE - 0.5f;
                    float sh = rp[2] * SCALE - 0.5f;
                    float bw = (rp[3] * SCALE - 0.5f - sw) * (1.0f / RS);
                    float bh = (rp[4] * SCALE - 0.5f - sh) * (1.0f / RS);
                    out[(size_t)n * CH + cinA] =
                        psroi_sample_f32(baseA, sw, sh, bw, bh, ph, pw);
                    out[(size_t)n * CH + cinA + 245] =
                        psroi_sample_f32(baseB, sw, sh, bw, bh, ph, pw);
                }
                ++seen;
            }
        }
    }
}

// ---- general fallback (any B / N > MAXN): direct-gather per output ----
__global__ __launch_bounds__(256) void psroi_naive_kernel(
    const float* __restrict__ feat, const float* __restrict__ rois,
    float* __restrict__ out, int total)
{
    int o = blockIdx.x * blockDim.x + threadIdx.x;
    if (o >= total) return;
    int cin = o % CH;
    int n   = o / CH;
    int pw  = cin % RS;
    int ph  = (cin / RS) % RS;
    const float* r = rois + (size_t)n * 5;
    int bidx = (int)r[0];
    float sw = r[1] * SCALE - 0.5f;
    float sh = r[2] * SCALE - 0.5f;
    float bw = (r[3] * SCALE - 0.5f - sw) * (1.0f / RS);
    float bh = (r[4] * SCALE - 0.5f - sh) * (1.0f / RS);
    const float* base = feat + (size_t)(bidx * CH + cin) * NPLANE;
    out[o] = psroi_sample_f32(base, sw, sh, bw, bh, ph, pw);
}

extern "C" void kernel_launch(void* const* d_in, const int* in_sizes, int n_in,
                              void* d_out, int out_size, void* d_ws, size_t ws_size,
                              hipStream_t stream) {
    const float* feat = (const float*)d_in[0];
    const float* rois = (const float*)d_in[1];
    float* out = (float*)d_out;
    int N = in_sizes[1] / 5;
    int B = in_sizes[0] / (CH * NPLANE);

    if (N <= MAXN && B == 4) {
        psroi_pair_pipe_kernel<<<NBLK, TPB, 0, stream>>>(feat, rois, out, N);
    } else {
        int total = N * CH;
        psroi_naive_kernel<<<(total + 255) / 256, 256, 0, stream>>>(feat, rois, out, total);
    }
}

// Round 20
// 26.151 us; speedup vs baseline: 1.0879x; 1.0879x over previous
//
#include <hip/hip_runtime.h>

#define RS 7
#define SR 2
#define PD 10
#define CH 490
#define SCALE (1.0f / 16.0f)
#define HH 100
#define WW 100
#define NPLANE 10000
#define SLOTS 2560            // 16B slots per buffer (data 2500 + pad)
#define BUFF (SLOTS * 4)      // 10240 floats = 40.96 KB; 3 bufs = 122.9 KB
#define TPB 1024
#define NBLK 256
#define NB 4
#define MAXN 4096
#define RSL 2                 // register param slots (covers cnt <= 2048)

// async global->LDS, 16B per lane; LDS dest WAVE-UNIFORM base (+lane*16 by HW)
__device__ __forceinline__ void gll16(const void* g, void* l) {
    __builtin_amdgcn_global_load_lds(
        (const __attribute__((address_space(1))) void*)g,
        (__attribute__((address_space(3))) void*)l, 16, 0, 0);
}

__device__ __forceinline__ void waitv(int allowed) {
    switch (allowed) {
        case 0: asm volatile("s_waitcnt vmcnt(0)" ::: "memory"); break;
        case 1: asm volatile("s_waitcnt vmcnt(1)" ::: "memory"); break;
        case 2: asm volatile("s_waitcnt vmcnt(2)" ::: "memory"); break;
        case 3: asm volatile("s_waitcnt vmcnt(3)" ::: "memory"); break;
        case 4: asm volatile("s_waitcnt vmcnt(4)" ::: "memory"); break;
        case 5: asm volatile("s_waitcnt vmcnt(5)" ::: "memory"); break;
        default: asm volatile("s_waitcnt vmcnt(0)" ::: "memory"); break;
    }
}

__device__ __forceinline__ float psroi_sample_f32(const float* __restrict__ plane,
                                                  float sw, float sh, float bw, float bh,
                                                  int ph, int pw)
{
    float acc = 0.0f;
    #pragma unroll
    for (int iy = 0; iy < SR; ++iy) {
        float y  = sh + ((float)ph + ((float)iy + 0.5f) * (1.0f / SR)) * bh;
        bool  vy = (y >= -1.0f) && (y <= (float)HH);
        float yy = fmaxf(y, 0.0f);
        int   y0 = min((int)floorf(yy), HH - 1);
        int   y1 = min(y0 + 1, HH - 1);
        float yc = (y0 >= HH - 1) ? (float)y0 : yy;
        float ly = yc - (float)y0;
        float hy = 1.0f - ly;
        #pragma unroll
        for (int ix = 0; ix < SR; ++ix) {
            float x  = sw + ((float)pw + ((float)ix + 0.5f) * (1.0f / SR)) * bw;
            bool  vx = (x >= -1.0f) && (x <= (float)WW);
            float xx = fmaxf(x, 0.0f);
            int   x0 = min((int)floorf(xx), WW - 1);
            int   x1 = min(x0 + 1, WW - 1);
            float xc = (x0 >= WW - 1) ? (float)x0 : xx;
            float lx = xc - (float)x0;
            float hx = 1.0f - lx;
            float v00 = plane[y0 * WW + x0];
            float v01 = plane[y0 * WW + x1];
            float v10 = plane[y1 * WW + x0];
            float v11 = plane[y1 * WW + x1];
            float v = hy * (hx * v00 + lx * v01) + ly * (hx * v10 + lx * v11);
            if (vy && vx) acc += v;
        }
    }
    return acc * (1.0f / (SR * SR));
}

// persistent 3-buffer pipeline (R13 champion) + latency-flat fused scan:
// 256 blocks (1/CU) x 1024 thr, 7-8 plane tiles per block, cin stride 32.
__global__ __launch_bounds__(TPB) void psroi_pipe_kernel(
    const float* __restrict__ feat, const float* __restrict__ rois,
    float* __restrict__ out, int N)
{
    __shared__ __align__(16) float buf0[BUFF];
    __shared__ __align__(16) float buf1[BUFF];
    __shared__ __align__(16) float buf2[BUFF];   // doubles as scan scratch
    __shared__ int lcnt;

    int tid  = threadIdx.x;
    int wid  = tid >> 6;
    int lane = tid & 63;
    int bid  = blockIdx.x;
    int xcd  = bid & 7;                 // heuristic XCD id (perf-only)
    int j    = bid >> 3;                // 0..31
    int b    = xcd >> 1;                // batch per half-slice pair
    int cin0 = (xcd & 1) * 245 + j;     // tiles: cin0 + k*32
    int ntile = (244 - j) / 32 + 1;     // 8 (j<=20) or 7

    if (tid == 0) lcnt = 0;
    __syncthreads();

    // ---- 1) latency-flat scan: prefetch FULL roi rows, then ballot-compact,
    //         writing finished params into LDS (no second global pass) ----
    float q0[4], q1[4], q2[4], q3[4], q4[4];
    #pragma unroll
    for (int s = 0; s < 4; ++s) {
        int k = s * TPB + tid;
        q0[s] = -1.0f;
        if (k < N) {
            const float* rp = rois + (size_t)k * 5;
            q0[s] = rp[0]; q1[s] = rp[1]; q2[s] = rp[2]; q3[s] = rp[3]; q4[s] = rp[4];
        }
    }
    float4* plds = (float4*)buf2;                  // 2048 float4 = 32 KB
    int*    nlds = (int*)(buf2 + 8192);            // 2048 int    =  8 KB
    #pragma unroll
    for (int s = 0; s < 4; ++s) {
        int k = s * TPB + tid;
        bool m = (k < N) && ((int)q0[s] == b);
        unsigned long long msk = __ballot(m);
        if (m) {
            int rank   = __popcll(msk & ((1ull << lane) - 1ull));
            int leader = __ffsll((long long)msk) - 1;
            int pos = 0;
            if (lane == leader) pos = atomicAdd(&lcnt, (int)__popcll(msk));
            pos = __shfl(pos, leader) + rank;
            if (pos < RSL * TPB) {
                float sw = q1[s] * SCALE - 0.5f;
                float sh = q2[s] * SCALE - 0.5f;
                float bw = (q3[s] * SCALE - 0.5f - sw) * (1.0f / RS);
                float bh = (q4[s] * SCALE - 0.5f - sh) * (1.0f / RS);
                plds[pos] = make_float4(sw, sh, bw, bh);
                nlds[pos] = k;
            }
        }
    }
    __syncthreads();
    int cnt = lcnt;

    // ---- 2) my ROI params -> registers (LDS only; no vmem) ----
    float psw[RSL], psh[RSL], pbw[RSL], pbh[RSL];
    int   pn[RSL];
    #pragma unroll
    for (int s = 0; s < RSL; ++s) {
        int i = tid + s * TPB;
        pn[s] = -1;
        psw[s] = psh[s] = pbw[s] = pbh[s] = 0.0f;
        if (i < cnt) {
            float4 p = plds[i];
            pn[s] = nlds[i];
            psw[s] = p.x; psh[s] = p.y; pbw[s] = p.z; pbh[s] = p.w;
        }
    }

    // ---- pathological overflow (cnt > 2048): direct recompute, full drain ----
    if (cnt > RSL * TPB) {
        for (int k = 0; k < ntile; ++k) {
            int cin = cin0 + k * 32;
            int pw = cin % RS, ph = (cin / RS) % RS;
            const float* base = feat + (size_t)(b * CH + cin) * NPLANE;
            for (int n = tid; n < N; n += TPB) {
                const float* rp = rois + (size_t)n * 5;
                if ((int)rp[0] != b) continue;
                float sw = rp[1] * SCALE - 0.5f;
                float sh = rp[2] * SCALE - 0.5f;
                float bw = (rp[3] * SCALE - 0.5f - sw) * (1.0f / RS);
                float bh = (rp[4] * SCALE - 0.5f - sh) * (1.0f / RS);
                out[(size_t)n * CH + cin] =
                    psroi_sample_f32(base, sw, sh, bw, bh, ph, pw);
            }
        }
        asm volatile("s_waitcnt vmcnt(0)" ::: "memory");
    }

    // wave-uniform store-instruction count per tile
    int wave_first = tid & ~63;
    int trips = 0;
    #pragma unroll
    for (int s = 0; s < RSL; ++s) if (wave_first + s * TPB < cnt) ++trips;

    // ---- 3) stage: exactly 3 glls per wave (rounds 0,1 full; round 2 dup) ----
    auto stage = [&](float* dst, int cin) {
        const char* gs = (const char*)(feat + (size_t)(b * CH + cin) * NPLANE);
        char* ls = (char*)dst;
        int wb = wid << 6;
        gll16(gs + (size_t)(tid) * 16,       ls + (size_t)(wb) * 16);
        gll16(gs + (size_t)(TPB + tid) * 16, ls + (size_t)(TPB + wb) * 16);
        int s2b = 2048 + ((wid & 7) << 6);           // waves w, w+8 duplicate
        int g2  = min(s2b + lane, 2499);             // clamp: pad gets finite junk
        gll16(gs + (size_t)g2 * 16,          ls + (size_t)s2b * 16);
    };

    stage(buf0, cin0);
    if (ntile > 1) stage(buf1, cin0 + 32);
    waitv(ntile > 1 ? 3 : 0);           // tile0 resident; tile1 in flight
    __builtin_amdgcn_s_barrier();       // also: all prologue LDS reads done
    __builtin_amdgcn_sched_barrier(0);

    // ---- 4) pipelined tile loop (3 buffers, 2-ahead issuance) ----
    for (int k = 0; k < ntile; ++k) {
        const float* __restrict__ bc = (k % 3 == 0) ? buf0 : ((k % 3 == 1) ? buf1 : buf2);
        if (k + 2 < ntile) {
            float* bn = ((k + 2) % 3 == 0) ? buf0 : (((k + 2) % 3 == 1) ? buf1 : buf2);
            stage(bn, cin0 + (k + 2) * 32);
        }
        __builtin_amdgcn_sched_barrier(0);

        int cin = cin0 + k * 32;
        int pw  = cin % RS;
        int ph  = (cin / RS) % RS;

        #pragma unroll
        for (int s = 0; s < RSL; ++s) {
            if (pn[s] >= 0) {
                float sw = psw[s], sh = psh[s], bw = pbw[s], bh = pbh[s];
                float acc = 0.0f;
                #pragma unroll
                for (int iy = 0; iy < SR; ++iy) {
                    float y  = sh + ((float)ph + ((float)iy + 0.5f) * (1.0f / SR)) * bh;
                    bool  vy = (y >= -1.0f) && (y <= (float)HH);
                    float yy = fmaxf(y, 0.0f);
                    int   y0 = min((int)floorf(yy), HH - 1);
                    float yc = (y0 >= HH - 1) ? (float)y0 : yy;
                    float ly = yc - (float)y0;
                    float hy = 1.0f - ly;
                    #pragma unroll
                    for (int ix = 0; ix < SR; ++ix) {
                        float x  = sw + ((float)pw + ((float)ix + 0.5f) * (1.0f / SR)) * bw;
                        bool  vx = (x >= -1.0f) && (x <= (float)WW);
                        float xx = fmaxf(x, 0.0f);
                        int   x0 = min((int)floorf(xx), WW - 1);
                        float xc = (x0 >= WW - 1) ? (float)x0 : xx;
                        float lx = xc - (float)x0;
                        float hx = 1.0f - lx;
                        // clamp-by-weight: stray taps (pad/junk) carry weight 0
                        int o = y0 * WW + x0;
                        float v00 = bc[o],      v01 = bc[o + 1];
                        float v10 = bc[o + WW], v11 = bc[o + WW + 1];
                        float v = hy * (hx * v00 + lx * v01) + ly * (hx * v10 + lx * v11);
                        if (vy && vx) acc += v;
                    }
                }
                out[(size_t)pn[s] * CH + cin] = acc * (1.0f / (SR * SR));
            }
        }

        if (k + 1 < ntile) {
            // retire own stage(k+1) glls; allow stage(k+2) glls + own stores
            waitv(trips + ((k + 2 < ntile) ? 3 : 0));
            __builtin_amdgcn_s_barrier();
            __builtin_amdgcn_sched_barrier(0);
        }
    }
}

// ---- general fallback (any B / N > MAXN): direct-gather per output ----
__global__ __launch_bounds__(256) void psroi_naive_kernel(
    const float* __restrict__ feat, const float* __restrict__ rois,
    float* __restrict__ out, int total)
{
    int o = blockIdx.x * blockDim.x + threadIdx.x;
    if (o >= total) return;
    int cin = o % CH;
    int n   = o / CH;
    int pw  = cin % RS;
    int ph  = (cin / RS) % RS;
    const float* r = rois + (size_t)n * 5;
    int bidx = (int)r[0];
    float sw = r[1] * SCALE - 0.5f;
    float sh = r[2] * SCALE - 0.5f;
    float bw = (r[3] * SCALE - 0.5f - sw) * (1.0f / RS);
    float bh = (r[4] * SCALE - 0.5f - sh) * (1.0f / RS);
    const float* base = feat + (size_t)(bidx * CH + cin) * NPLANE;
    out[o] = psroi_sample_f32(base, sw, sh, bw, bh, ph, pw);
}

extern "C" void kernel_launch(void* const* d_in, const int* in_sizes, int n_in,
                              void* d_out, int out_size, void* d_ws, size_t ws_size,
                              hipStream_t stream) {
    const float* feat = (const float*)d_in[0];
    const float* rois = (const float*)d_in[1];
    float* out = (float*)d_out;
    int N = in_sizes[1] / 5;
    int B = in_sizes[0] / (CH * NPLANE);

    if (N <= MAXN && B == 4) {
        psroi_pipe_kernel<<<NBLK, TPB, 0, stream>>>(feat, rois, out, N);
    } else {
        int total = N * CH;
        psroi_naive_kernel<<<(total + 255) / 256, 256, 0, stream>>>(feat, rois, out, total);
    }
}